// Round 5
// baseline (11255.596 us; speedup 1.0000x reference)
//
#include <hip/hip_runtime.h>
#include <hip/hip_bf16.h>
#include <math.h>

// SimplifiedCTM on MI355X — round 5: f32 inputs, **f32 output** (evidence:
// out npz size matches f32 exactly; bit-identical error across r2/r3/r4 was the
// bf16-write-read-as-f32 distortion). Math unchanged from r4 (audited 4x).

#define DEV __device__ __forceinline__
typedef const float* fp;

#define B_   16
#define P_   196
#define D_   512
#define H_   8
#define HD_  64
#define N_   2048
#define M_   25
#define SA_  512
#define SO_  1024
#define O_   1000
#define T_   16

DEV float sigmf(float x){ return 1.0f / (1.0f + expf(-x)); }

DEV float dot_f(const float* s, const float* w, int n) {
  const float4* wp = reinterpret_cast<const float4*>(w);
  float acc = 0.f;
  for (int i = 0; i < n; i += 8) {
    float4 u = wp[i >> 2];
    float4 v = wp[(i >> 2) + 1];
    acc += s[i+0]*u.x; acc += s[i+1]*u.y;
    acc += s[i+2]*u.z; acc += s[i+3]*u.w;
    acc += s[i+4]*v.x; acc += s[i+5]*v.y;
    acc += s[i+6]*v.z; acc += s[i+7]*v.w;
  }
  return acc;
}

DEV float breduce_sum(float v, float* red) {
  int t = threadIdx.x;
  red[t] = v; __syncthreads();
  for (int s = blockDim.x >> 1; s > 0; s >>= 1) {
    if (t < s) red[t] += red[t + s];
    __syncthreads();
  }
  float r = red[0]; __syncthreads();
  return r;
}
DEV float breduce_max(float v, float* red) {
  int t = threadIdx.x;
  red[t] = v; __syncthreads();
  for (int s = blockDim.x >> 1; s > 0; s >>= 1) {
    if (t < s) red[t] = fmaxf(red[t], red[t + s]);
    __syncthreads();
  }
  float r = red[0]; __syncthreads();
  return r;
}

// ---- P1: patch conv (as GEMM) + LN + pos -> pt (B*P, D) ----
__global__ __launch_bounds__(256) void k_patch(fp x, fp conv_w, fp conv_b,
                                               fp ln_g, fp ln_b, fp pos, float* pt) {
  int bp = blockIdx.x;
  int b = bp / P_, p = bp % P_;
  int ph = p / 14, pw = p % 14;
  int tid = threadIdx.x;
  __shared__ float patch[768];
  __shared__ float red[256];
  for (int j = tid; j < 768; j += 256) {
    int ci = j >> 8, r = j & 255, pi = r >> 4, pj = r & 15;
    patch[j] = x[((size_t)(b*3 + ci)*224 + (ph*16 + pi))*224 + (pw*16 + pj)];
  }
  __syncthreads();
  float a0 = conv_b[tid]       + dot_f(patch, conv_w + (size_t)tid*768, 768);
  float a1 = conv_b[tid + 256] + dot_f(patch, conv_w + (size_t)(tid + 256)*768, 768);
  float S  = breduce_sum(a0 + a1, red);
  float Q  = breduce_sum(a0*a0 + a1*a1, red);
  float mu = S / (float)D_;
  float var = Q / (float)D_ - mu*mu;
  float rstd = 1.f / sqrtf(var + 1e-5f);
  pt[(size_t)bp*D_ + tid]       = (a0 - mu)*rstd*ln_g[tid]       + ln_b[tid]       + pos[p*D_ + tid];
  pt[(size_t)bp*D_ + tid + 256] = (a1 - mu)*rstd*ln_g[tid + 256] + ln_b[tid + 256] + pos[p*D_ + tid + 256];
}

// ---- P2: kv = LN(pt @ kv_w.T + kv_b) ----
__global__ __launch_bounds__(256) void k_kv(const float* pt, fp kv_w, fp kv_b,
                                            fp g, fp bb, float* kv) {
  int bp = blockIdx.x, tid = threadIdx.x;
  __shared__ float row[512];
  __shared__ float red[256];
  row[tid]       = pt[(size_t)bp*D_ + tid];
  row[tid + 256] = pt[(size_t)bp*D_ + tid + 256];
  __syncthreads();
  float a0 = kv_b[tid]       + dot_f(row, kv_w + (size_t)tid*512, 512);
  float a1 = kv_b[tid + 256] + dot_f(row, kv_w + (size_t)(tid + 256)*512, 512);
  float S  = breduce_sum(a0 + a1, red);
  float Q  = breduce_sum(a0*a0 + a1*a1, red);
  float mu = S / (float)D_;
  float var = Q / (float)D_ - mu*mu;
  float rstd = 1.f / sqrtf(var + 1e-5f);
  kv[(size_t)bp*D_ + tid]       = (a0 - mu)*rstd*g[tid]       + bb[tid];
  kv[(size_t)bp*D_ + tid + 256] = (a1 - mu)*rstd*g[tid + 256] + bb[tid + 256];
}

// ---- INIT ----
__global__ void k_init(fp start_state, fp start_trace, const int* oL, const int* oR,
                       float* act, float* trace, float* aa, float* ba, float* ao, float* bo) {
  int gid = blockIdx.x * 256 + threadIdx.x;
  if (gid < B_*N_*M_) {
    int bn = gid / M_, m = gid % M_;
    int n = bn % N_;
    trace[gid] = start_trace[n*M_ + m];
  }
  if (gid < B_*N_) act[gid] = start_state[gid & (N_-1)];
  if (gid < B_*SA_) { aa[gid] = 0.f; ba[gid] = 0.f; }
  if (gid < B_*SO_) {
    int s = gid & (SO_-1);
    float l = start_state[oL[s]];
    float r = start_state[oR[s]];
    ao[gid] = l*r; bo[gid] = 1.0f;
  }
}

// ---- T1: action sync + q projections ----
__global__ __launch_bounds__(256) void k_syncq(const float* act, float* aa, float* ba,
                                               fp decay_a, const int* L, const int* R,
                                               fp q_w, fp q_b, fp aw, fp ab, float* qh) {
  int b = blockIdx.x, tid = threadIdx.x;
  __shared__ float sact[512];
  __shared__ float qv[512];
  for (int cc = 0; cc < 2; cc++) {
    int s_ = tid + cc*256;
    float r = expf(-decay_a[s_]);
    float pair = act[b*N_ + L[s_]] * act[b*N_ + R[s_]];
    float a  = r*aa[b*SA_ + s_] + pair;
    float bt = r*ba[b*SA_ + s_] + 1.0f;
    aa[b*SA_ + s_] = a; ba[b*SA_ + s_] = bt;
    sact[s_] = a / sqrtf(bt);
  }
  __syncthreads();
  for (int cc = 0; cc < 2; cc++) {
    int j = tid + cc*256;
    qv[j] = q_b[j] + dot_f(sact, q_w + (size_t)j*512, 512);
  }
  __syncthreads();
  for (int cc = 0; cc < 2; cc++) {
    int j = tid + cc*256;
    float v = ab[j] + dot_f(qv, aw + (size_t)j*512, 512);
    qh[b*D_ + j] = v * 0.125f;  // 1/sqrt(hd=64)
  }
}

// ---- T2: rank-space attention on kv panel (K/V never materialized) ----
__global__ __launch_bounds__(512) void k_attn(const float* qh, const float* kvb,
                                              fp aw, fp ab, fp ow, fp ob, float* attn_o) {
  int b = blockIdx.x, tid = threadIdx.x;
  int h = tid >> 6, lane = tid & 63;
  __shared__ float qs[512];
  __shared__ float qt[H_][512];
  __shared__ float sc[H_][200];
  __shared__ float zz[H_][512];
  __shared__ float attnv[512];
  __shared__ float hsum[H_];
  qs[tid] = qh[b*D_ + tid];
  __syncthreads();
  float kb = 0.f;
  for (int e = 0; e < HD_; e++) kb += qs[h*HD_ + e] * ab[512 + h*HD_ + e];
  for (int cc = 0; cc < 8; cc++) {
    int c = lane + cc*64;
    float s = 0.f;
    for (int e = 0; e < HD_; e++) s += qs[h*HD_ + e] * aw[(size_t)(512 + h*HD_ + e)*D_ + c];
    qt[h][c] = s;
  }
  __syncthreads();
  for (int p = lane; p < P_; p += 64) {
    const float* kvp = kvb + ((size_t)(b*P_ + p))*D_;
    float s = kb;
    for (int c = 0; c < D_; c++) s += qt[h][c] * kvp[c];
    sc[h][p] = s;
  }
  __syncthreads();
  if (lane == 0) {
    float m = -1e30f;
    for (int p = 0; p < P_; p++) m = fmaxf(m, sc[h][p]);
    float ss = 0.f;
    for (int p = 0; p < P_; p++) { float e = expf(sc[h][p] - m); sc[h][p] = e; ss += e; }
    hsum[h] = ss;
  }
  __syncthreads();
  float inv = 1.f / hsum[h];
  for (int cc = 0; cc < 8; cc++) {
    int c = lane + cc*64;
    float s = 0.f;
    for (int p = 0; p < P_; p++) s += sc[h][p] * kvb[((size_t)(b*P_ + p))*D_ + c];
    zz[h][c] = s * inv;
  }
  __syncthreads();
  {
    float s = ab[1024 + tid];
    const float* wr = aw + (size_t)(1024 + tid)*D_;
    for (int c = 0; c < D_; c++) s += zz[h][c] * wr[c];
    attnv[tid] = s;
  }
  __syncthreads();
  attn_o[b*D_ + tid] = ob[tid] + dot_f(attnv, ow + (size_t)tid*D_, 512);
}

// ---- T3: y = pre @ syn_w.T + syn_b ----
__global__ __launch_bounds__(256) void k_syn(const float* attn_o, const float* act,
                                             fp syn_w, fp syn_b, float* y) {
  int chunk = blockIdx.x, b = blockIdx.y, tid = threadIdx.x;
  __shared__ float pre[2560];
  for (int i = tid; i < 2560; i += 256)
    pre[i] = (i < 512) ? attn_o[b*D_ + i] : act[b*N_ + (i - 512)];
  __syncthreads();
  int o = chunk*256 + tid;
  y[b*4096 + o] = syn_b[o] + dot_f(pre, syn_w + (size_t)o*2560, 2560);
}

// ---- T4: GLU + LN -> state; trace shift-append ----
__global__ __launch_bounds__(256) void k_gluln(const float* y, fp g, fp bvec, float* trace) {
  int b = blockIdx.x, tid = threadIdx.x;
  __shared__ float st[2048];
  __shared__ float red[256];
  float ls = 0.f, lq = 0.f;
  for (int ii = 0; ii < 8; ii++) {
    int c = ii*256 + tid;
    float a  = y[b*4096 + c];
    float gg = y[b*4096 + 2048 + c];
    float v = a * sigmf(gg);
    st[c] = v; ls += v; lq += v*v;
  }
  float S = breduce_sum(ls, red);
  float Q = breduce_sum(lq, red);
  float mu = S / (float)N_;
  float var = Q / (float)N_ - mu*mu;
  float rstd = 1.f / sqrtf(var + 1e-5f);
  for (int ii = 0; ii < 8; ii++) {
    int c = ii*256 + tid;
    float sv = (st[c] - mu)*rstd*g[c] + bvec[c];
    float* tp = trace + ((size_t)(b*N_ + c))*M_;
    for (int m = 0; m < M_-1; m++) tp[m] = tp[m+1];
    tp[M_-1] = sv;
  }
}

// ---- T5: NLM per neuron ----
__global__ __launch_bounds__(256) void k_nlm(const float* trace, fp fc1_w, fp fc1_b,
                                             fp fc2_w, fp fc2_b, fp nlmT, float* act) {
  int n = blockIdx.x, tid = threadIdx.x;
  __shared__ float tr[B_][M_];
  __shared__ float uu[256][17];
  __shared__ float h1[128][17];
  __shared__ float vout[B_][2];
  for (int i = tid; i < B_*M_; i += 256) {
    int b = i / M_, m = i % M_;
    tr[b][m] = trace[((size_t)(b*N_ + n))*M_ + m];
  }
  __syncthreads();
  float w25[M_];
  for (int m = 0; m < M_; m++) w25[m] = fc1_w[((size_t)n*M_ + m)*256 + tid];
  float bias = fc1_b[n*256 + tid];
  for (int b = 0; b < B_; b++) {
    float u = bias;
    for (int m = 0; m < M_; m++) u += tr[b][m]*w25[m];
    uu[tid][b] = u;
  }
  __syncthreads();
  if (tid < 128) {
    for (int b = 0; b < B_; b++)
      h1[tid][b] = uu[tid][b] * sigmf(uu[tid + 128][b]);
  }
  __syncthreads();
  if (tid < 32) {
    int b = tid >> 1, o = tid & 1;
    float acc = fc2_b[n*2 + o];
    for (int hh = 0; hh < 128; hh++) acc += h1[hh][b] * fc2_w[((size_t)n*128 + hh)*2 + o];
    vout[b][o] = acc;
  }
  __syncthreads();
  if (tid < B_) {
    act[tid*N_ + n] = vout[tid][0] * sigmf(vout[tid][1]) / nlmT[0];
  }
}

// ---- T6: out sync + pred GEMM ----
__global__ __launch_bounds__(256) void k_outsync(const float* act, float* ao, float* bo,
                                                 fp decay_o, const int* L, const int* R,
                                                 fp out_w, fp out_b, float* predsf, int t) {
  int b = blockIdx.x, tid = threadIdx.x;
  __shared__ float sout[1024];
  for (int cc = 0; cc < 4; cc++) {
    int s_ = tid + cc*256;
    float r = expf(-decay_o[s_]);
    float pair = act[b*N_ + L[s_]] * act[b*N_ + R[s_]];
    float a  = r*ao[b*SO_ + s_] + pair;
    float bt = r*bo[b*SO_ + s_] + 1.f;
    ao[b*SO_ + s_] = a; bo[b*SO_ + s_] = bt;
    sout[s_] = a / sqrtf(bt);
  }
  __syncthreads();
  for (int cc = 0; cc < 4; cc++) {
    int o = tid + cc*256;
    if (o < O_)
      predsf[((size_t)(t*B_ + b))*O_ + o] = out_b[o] + dot_f(sout, out_w + (size_t)o*1024, 1024);
  }
}

// ---- T7: entropy + f32 output writes ----
__global__ __launch_bounds__(256) void k_final(const float* predsf, float* out) {
  int b = blockIdx.x, t = blockIdx.y, tid = threadIdx.x;
  __shared__ float red[256];
  const float* p = predsf + ((size_t)(t*B_ + b))*O_;
  float lm = -1e30f;
  for (int o = tid; o < O_; o += 256) lm = fmaxf(lm, p[o]);
  float Mx = breduce_max(lm, red);
  float le = 0.f;
  for (int o = tid; o < O_; o += 256) le += expf(p[o] - Mx);
  float S = breduce_sum(le, red);
  float lt = 0.f;
  for (int o = tid; o < O_; o += 256) {
    float pr = expf(p[o] - Mx) / S;
    lt += pr * logf(pr + 1e-10f);
  }
  float E = breduce_sum(lt, red);
  float ent = -E / logf((float)O_);
  for (int o = tid; o < O_; o += 256)
    out[(size_t)b*O_*T_ + (size_t)o*T_ + t] = p[o];
  if (tid == 0)
    out[(size_t)B_*O_*T_ + b*T_ + t] = ent;
}

extern "C" void kernel_launch(void* const* d_in, const int* in_sizes, int n_in,
                              void* d_out, int out_size, void* d_ws, size_t ws_size,
                              hipStream_t stream) {
  (void)in_sizes; (void)n_in; (void)out_size; (void)ws_size;
  fp x          = (fp)d_in[0];
  fp conv_w     = (fp)d_in[1];
  fp conv_b     = (fp)d_in[2];
  fp patch_ln_g = (fp)d_in[3];
  fp patch_ln_b = (fp)d_in[4];
  fp pos        = (fp)d_in[5];
  fp kv_w       = (fp)d_in[6];
  fp kv_b       = (fp)d_in[7];
  fp kv_ln_g    = (fp)d_in[8];
  fp kv_ln_b    = (fp)d_in[9];
  fp q_w        = (fp)d_in[10];
  fp q_b        = (fp)d_in[11];
  fp attn_in_w  = (fp)d_in[12];
  fp attn_in_b  = (fp)d_in[13];
  fp attn_out_w = (fp)d_in[14];
  fp attn_out_b = (fp)d_in[15];
  fp syn_w      = (fp)d_in[16];
  fp syn_b      = (fp)d_in[17];
  fp syn_ln_g   = (fp)d_in[18];
  fp syn_ln_b   = (fp)d_in[19];
  fp fc1_w      = (fp)d_in[20];
  fp fc1_b      = (fp)d_in[21];
  fp fc2_w      = (fp)d_in[22];
  fp fc2_b      = (fp)d_in[23];
  fp nlm_T      = (fp)d_in[24];
  fp start_state= (fp)d_in[25];
  fp start_trace= (fp)d_in[26];
  fp decay_a    = (fp)d_in[27];
  fp decay_o    = (fp)d_in[28];
  fp out_w      = (fp)d_in[29];
  fp out_b      = (fp)d_in[30];
  const int* act_left  = (const int*)d_in[31];
  const int* act_right = (const int*)d_in[32];
  const int* out_left  = (const int*)d_in[33];
  const int* out_right = (const int*)d_in[34];

  float* ws = (float*)d_ws;
  float* X   = ws;
  float* kvb = ws + (size_t)B_*P_*D_;          // 1,605,632 floats

  float* pt     = X;                           // precompute only (dead after k_kv)
  float* predsf = X;                           // 256,000
  float* act    = X + 256000;                  // 32,768
  float* trace  = X + 288768;                  // 819,200
  float* aa     = X + 1107968;                 // 8,192
  float* ba     = X + 1116160;                 // 8,192
  float* ao     = X + 1124352;                 // 16,384
  float* bo     = X + 1140736;                 // 16,384
  float* qh     = X + 1157120;                 // 8,192
  float* attn_o = X + 1165312;                 // 8,192
  float* ysyn   = X + 1173504;                 // 65,536 -> ends 1,239,040 < 1,605,632

  k_patch<<<dim3(B_*P_), dim3(256), 0, stream>>>(x, conv_w, conv_b, patch_ln_g, patch_ln_b, pos, pt);
  k_kv<<<dim3(B_*P_), dim3(256), 0, stream>>>(pt, kv_w, kv_b, kv_ln_g, kv_ln_b, kvb);
  k_init<<<dim3((B_*N_*M_ + 255)/256), dim3(256), 0, stream>>>(start_state, start_trace,
        out_left, out_right, act, trace, aa, ba, ao, bo);

  for (int t = 0; t < T_; t++) {
    k_syncq<<<dim3(B_), dim3(256), 0, stream>>>(act, aa, ba, decay_a, act_left, act_right,
                                                q_w, q_b, attn_in_w, attn_in_b, qh);
    k_attn<<<dim3(B_), dim3(512), 0, stream>>>(qh, kvb, attn_in_w, attn_in_b,
                                               attn_out_w, attn_out_b, attn_o);
    k_syn<<<dim3(16, B_), dim3(256), 0, stream>>>(attn_o, act, syn_w, syn_b, ysyn);
    k_gluln<<<dim3(B_), dim3(256), 0, stream>>>(ysyn, syn_ln_g, syn_ln_b, trace);
    k_nlm<<<dim3(N_), dim3(256), 0, stream>>>(trace, fc1_w, fc1_b, fc2_w, fc2_b, nlm_T, act);
    k_outsync<<<dim3(B_), dim3(256), 0, stream>>>(act, ao, bo, decay_o, out_left, out_right,
                                                  out_w, out_b, predsf, t);
  }
  k_final<<<dim3(B_, T_), dim3(256), 0, stream>>>(predsf, (float*)d_out);
}

// Round 6
// 10825.984 us; speedup vs baseline: 1.0397x; 1.0397x over previous
//
#include <hip/hip_runtime.h>
#include <hip/hip_bf16.h>
#include <math.h>

// SimplifiedCTM on MI355X — round 6: wave-cooperative coalesced GEMVs everywhere,
// attention parallelized over (b,h), syn batched 8x in LDS, trace shift fused
// into nlm. f32 in / f32 out. ws = 12.25 MiB (unchanged, proven).

#define DEV __device__ __forceinline__
typedef const float* fp;

#define B_   16
#define P_   196
#define D_   512
#define H_   8
#define HD_  64
#define N_   2048
#define M_   25
#define SA_  512
#define SO_  1024
#define O_   1000
#define T_   16

DEV float sigmf(float x){ return 1.0f / (1.0f + expf(-x)); }

DEV float wred(float v) {           // 64-lane butterfly sum
  for (int m = 32; m; m >>= 1) v += __shfl_xor(v, m);
  return v;
}
DEV float f4dot(float4 a, float4 b) {
  return a.x*b.x + a.y*b.y + a.z*b.z + a.w*b.w;
}

DEV float breduce_sum(float v, float* red) {
  int t = threadIdx.x;
  red[t] = v; __syncthreads();
  for (int s = blockDim.x >> 1; s > 0; s >>= 1) {
    if (t < s) red[t] += red[t + s];
    __syncthreads();
  }
  float r = red[0]; __syncthreads();
  return r;
}
DEV float breduce_max(float v, float* red) {
  int t = threadIdx.x;
  red[t] = v; __syncthreads();
  for (int s = blockDim.x >> 1; s > 0; s >>= 1) {
    if (t < s) red[t] = fmaxf(red[t], red[t + s]);
    __syncthreads();
  }
  float r = red[0]; __syncthreads();
  return r;
}

// ---- P1: patch conv + LN + pos. 4 patches/block, wave-coop rows. ----
__global__ __launch_bounds__(256) void k_patch(fp x, fp conv_w, fp conv_b,
                                               fp ln_g, fp ln_b, fp pos, float* pt) {
  int g = blockIdx.x;               // 784 blocks, 4 patches each
  int bp0 = g * 4;
  int b = bp0 / P_, p0 = bp0 % P_;
  int tid = threadIdx.x, wave = tid >> 6, lane = tid & 63;
  __shared__ float patch[4][768];
  __shared__ float aL[4][512];
  __shared__ float red[256];
  for (int pi = 0; pi < 4; pi++) {
    int p = p0 + pi, ph = p / 14, pw = p % 14;
    for (int j = tid; j < 768; j += 256) {
      int ci = j >> 8, r = j & 255, qi = r >> 4, qj = r & 15;
      patch[pi][j] = x[((size_t)(b*3 + ci)*224 + (ph*16 + qi))*224 + (pw*16 + qj)];
    }
  }
  __syncthreads();
  for (int r = wave*128; r < wave*128 + 128; r++) {
    const float* wr = conv_w + (size_t)r*768 + lane*4;
    float4 w0 = *(const float4*)(wr);
    float4 w1 = *(const float4*)(wr + 256);
    float4 w2 = *(const float4*)(wr + 512);
    for (int pi = 0; pi < 4; pi++) {
      const float* pp = patch[pi] + lane*4;
      float s = f4dot(w0, *(const float4*)(pp))
              + f4dot(w1, *(const float4*)(pp + 256))
              + f4dot(w2, *(const float4*)(pp + 512));
      s = wred(s);
      if (lane == 0) aL[pi][r] = s + conv_b[r];
    }
  }
  __syncthreads();
  for (int pi = 0; pi < 4; pi++) {
    float a0 = aL[pi][tid], a1 = aL[pi][tid + 256];
    float S = breduce_sum(a0 + a1, red);
    float Q = breduce_sum(a0*a0 + a1*a1, red);
    float mu = S / (float)D_;
    float var = Q / (float)D_ - mu*mu;
    float rstd = 1.f / sqrtf(var + 1e-5f);
    int p = p0 + pi;
    size_t base = (size_t)(bp0 + pi) * D_;
    pt[base + tid]       = (a0 - mu)*rstd*ln_g[tid]       + ln_b[tid]       + pos[p*D_ + tid];
    pt[base + tid + 256] = (a1 - mu)*rstd*ln_g[tid + 256] + ln_b[tid + 256] + pos[p*D_ + tid + 256];
  }
}

// ---- P2: kv = LN(pt @ kv_w.T + kv_b). 4 rows/block, wave-coop. ----
__global__ __launch_bounds__(256) void k_kv(const float* pt, fp kv_w, fp kv_b,
                                            fp g, fp bb, float* kv) {
  int gblk = blockIdx.x;            // 784 blocks
  int bp0 = gblk * 4;
  int tid = threadIdx.x, wave = tid >> 6, lane = tid & 63;
  __shared__ float rin[4][512];
  __shared__ float aL[4][512];
  __shared__ float red[256];
  for (int pi = 0; pi < 4; pi++)
    for (int j = tid; j < 512; j += 256)
      rin[pi][j] = pt[(size_t)(bp0 + pi)*D_ + j];
  __syncthreads();
  for (int r = wave*128; r < wave*128 + 128; r++) {
    const float* wr = kv_w + (size_t)r*512 + lane*4;
    float4 w0 = *(const float4*)(wr);
    float4 w1 = *(const float4*)(wr + 256);
    for (int pi = 0; pi < 4; pi++) {
      const float* pp = rin[pi] + lane*4;
      float s = f4dot(w0, *(const float4*)(pp))
              + f4dot(w1, *(const float4*)(pp + 256));
      s = wred(s);
      if (lane == 0) aL[pi][r] = s + kv_b[r];
    }
  }
  __syncthreads();
  for (int pi = 0; pi < 4; pi++) {
    float a0 = aL[pi][tid], a1 = aL[pi][tid + 256];
    float S = breduce_sum(a0 + a1, red);
    float Q = breduce_sum(a0*a0 + a1*a1, red);
    float mu = S / (float)D_;
    float var = Q / (float)D_ - mu*mu;
    float rstd = 1.f / sqrtf(var + 1e-5f);
    size_t base = (size_t)(bp0 + pi) * D_;
    kv[base + tid]       = (a0 - mu)*rstd*g[tid]       + bb[tid];
    kv[base + tid + 256] = (a1 - mu)*rstd*g[tid + 256] + bb[tid + 256];
  }
}

// ---- INIT ----
__global__ void k_init(fp start_state, fp start_trace, const int* oL, const int* oR,
                       float* act, float* trace, float* aa, float* ba, float* ao, float* bo) {
  int gid = blockIdx.x * 256 + threadIdx.x;
  if (gid < B_*N_*M_) {
    int bn = gid / M_, m = gid % M_;
    int n = bn % N_;
    trace[gid] = start_trace[n*M_ + m];
  }
  if (gid < B_*N_) act[gid] = start_state[gid & (N_-1)];
  if (gid < B_*SA_) { aa[gid] = 0.f; ba[gid] = 0.f; }
  if (gid < B_*SO_) {
    int s = gid & (SO_-1);
    ao[gid] = start_state[oL[s]] * start_state[oR[s]];
    bo[gid] = 1.0f;
  }
}

// ---- T1: action sync + two wave-coop GEMVs -> qh ----
__global__ __launch_bounds__(256) void k_syncq(const float* act, float* aa, float* ba,
                                               fp decay_a, const int* L, const int* R,
                                               fp q_w, fp q_b, fp aw, fp ab, float* qh) {
  int b = blockIdx.x, tid = threadIdx.x, wave = tid >> 6, lane = tid & 63;
  __shared__ float sact[512];
  __shared__ float qv[512];
  for (int cc = 0; cc < 2; cc++) {
    int s_ = tid + cc*256;
    float r = expf(-decay_a[s_]);
    float pair = act[b*N_ + L[s_]] * act[b*N_ + R[s_]];
    float a  = r*aa[b*SA_ + s_] + pair;
    float bt = r*ba[b*SA_ + s_] + 1.0f;
    aa[b*SA_ + s_] = a; ba[b*SA_ + s_] = bt;
    sact[s_] = a / sqrtf(bt);
  }
  __syncthreads();
  for (int r = wave*128; r < wave*128 + 128; r++) {
    const float* wr = q_w + (size_t)r*512 + lane*4;
    const float* pp = sact + lane*4;
    float s = f4dot(*(const float4*)(wr),       *(const float4*)(pp))
            + f4dot(*(const float4*)(wr + 256), *(const float4*)(pp + 256));
    s = wred(s);
    if (lane == 0) qv[r] = s + q_b[r];
  }
  __syncthreads();
  for (int r = wave*128; r < wave*128 + 128; r++) {
    const float* wr = aw + (size_t)r*512 + lane*4;   // wq rows 0..511
    const float* pp = qv + lane*4;
    float s = f4dot(*(const float4*)(wr),       *(const float4*)(pp))
            + f4dot(*(const float4*)(wr + 256), *(const float4*)(pp + 256));
    s = wred(s);
    if (lane == 0) qh[b*D_ + r] = (s + ab[r]) * 0.125f;   // 1/sqrt(64)
  }
}

// ---- T2: rank-space attention, one block per (b,h) ----
// qt = qh_h @ wk_h (column-parallel, coalesced); scores wave-coop over patches;
// softmax block-wide; zz column-parallel. zz -> ws.
__global__ __launch_bounds__(256) void k_attn(const float* qh, const float* kvb,
                                              fp aw, fp ab, float* zz) {
  int b = blockIdx.x, h = blockIdx.y;
  int tid = threadIdx.x, wave = tid >> 6, lane = tid & 63;
  __shared__ float qhh[64];
  __shared__ float qt[512];
  __shared__ float sc[256];
  __shared__ float red[256];
  if (tid < 64) qhh[tid] = qh[b*D_ + h*HD_ + tid];
  __syncthreads();
  float acc0 = 0.f, acc1 = 0.f;
  for (int e = 0; e < HD_; e++) {
    float q = qhh[e];
    const float* ar = aw + (size_t)(512 + h*HD_ + e)*D_;
    acc0 += q * ar[tid];
    acc1 += q * ar[tid + 256];
  }
  qt[tid] = acc0; qt[tid + 256] = acc1;
  float kb = 0.f;
  for (int e = 0; e < HD_; e++) kb += qhh[e] * ab[512 + h*HD_ + e];
  __syncthreads();
  for (int p = wave*49; p < wave*49 + 49; p++) {
    const float* kvp = kvb + ((size_t)(b*P_ + p))*D_ + lane*4;
    const float* qq = qt + lane*4;
    float s = f4dot(*(const float4*)(kvp),       *(const float4*)(qq))
            + f4dot(*(const float4*)(kvp + 256), *(const float4*)(qq + 256));
    s = wred(s);
    if (lane == 0) sc[p] = s + kb;
  }
  __syncthreads();
  float v = (tid < P_) ? sc[tid] : -1e30f;
  float m = breduce_max(v, red);
  float e = (tid < P_) ? expf(sc[tid] - m) : 0.f;
  if (tid < P_) sc[tid] = e;
  float ssum = breduce_sum(e, red);
  float inv = 1.f / ssum;
  float z0 = 0.f, z1 = 0.f;
  for (int p = 0; p < P_; p++) {
    const float* kvp = kvb + ((size_t)(b*P_ + p))*D_;
    float w = sc[p];
    z0 += w * kvp[tid];
    z1 += w * kvp[tid + 256];
  }
  zz[(size_t)(b*H_ + h)*D_ + tid]       = z0 * inv;
  zz[(size_t)(b*H_ + h)*D_ + tid + 256] = z1 * inv;
}

// ---- T2b: attnv = zz @ wv.T + bv ; attn_o = attnv @ ow.T + ob ----
__global__ __launch_bounds__(256) void k_ao(const float* zz, fp aw, fp ab,
                                            fp ow, fp ob, float* attn_o) {
  int b = blockIdx.x, tid = threadIdx.x, wave = tid >> 6, lane = tid & 63;
  __shared__ float zzL[H_*512];
  __shared__ float av[512];
  for (int i = tid; i < H_*512; i += 256) zzL[i] = zz[(size_t)b*H_*512 + i];
  __syncthreads();
  for (int r = wave*128; r < wave*128 + 128; r++) {
    int h = r >> 6;
    const float* wr = aw + (size_t)(1024 + r)*512 + lane*4;
    const float* pp = zzL + h*512 + lane*4;
    float s = f4dot(*(const float4*)(wr),       *(const float4*)(pp))
            + f4dot(*(const float4*)(wr + 256), *(const float4*)(pp + 256));
    s = wred(s);
    if (lane == 0) av[r] = s + ab[1024 + r];
  }
  __syncthreads();
  for (int r = wave*128; r < wave*128 + 128; r++) {
    const float* wr = ow + (size_t)r*512 + lane*4;
    const float* pp = av + lane*4;
    float s = f4dot(*(const float4*)(wr),       *(const float4*)(pp))
            + f4dot(*(const float4*)(wr + 256), *(const float4*)(pp + 256));
    s = wred(s);
    if (lane == 0) attn_o[b*D_ + r] = s + ob[r];
  }
}

// ---- T3: y = pre @ syn_w.T + syn_b. Block = 128 rows x 8 batches. ----
__global__ __launch_bounds__(256) void k_syn(const float* attn_o, const float* act,
                                             fp syn_w, fp syn_b, float* y) {
  int rb = blockIdx.x;              // 32 row-blocks of 128
  int bg = blockIdx.y;              // 2 batch-groups of 8
  int tid = threadIdx.x, wave = tid >> 6, lane = tid & 63;
  __shared__ float pre8[8][2560];
  for (int bb = 0; bb < 8; bb++) {
    int b = bg*8 + bb;
    for (int i = tid; i < 2560; i += 256)
      pre8[bb][i] = (i < 512) ? attn_o[b*D_ + i] : act[b*N_ + (i - 512)];
  }
  __syncthreads();
  for (int k = 0; k < 32; k++) {
    int r = rb*128 + wave*32 + k;
    const float* wr = syn_w + (size_t)r*2560 + lane*4;
    float4 wreg[10];
    for (int j = 0; j < 10; j++) wreg[j] = *(const float4*)(wr + j*256);
    float pp[8] = {0,0,0,0,0,0,0,0};
    for (int j = 0; j < 10; j++) {
      int idx = lane*4 + j*256;
      for (int bb = 0; bb < 8; bb++)
        pp[bb] += f4dot(wreg[j], *(const float4*)(&pre8[bb][idx]));
    }
    float sb = syn_b[r];
    for (int bb = 0; bb < 8; bb++) {
      float s = wred(pp[bb]);
      if (lane == 0) y[(size_t)(bg*8 + bb)*4096 + r] = s + sb;
    }
  }
}

// ---- T4: GLU + LN -> state (no trace touch) ----
__global__ __launch_bounds__(256) void k_state(const float* y, fp g, fp bvec, float* state) {
  int b = blockIdx.x, tid = threadIdx.x;
  __shared__ float st[2048];
  __shared__ float red[256];
  float ls = 0.f, lq = 0.f;
  for (int ii = 0; ii < 8; ii++) {
    int c = ii*256 + tid;
    float a  = y[(size_t)b*4096 + c];
    float gg = y[(size_t)b*4096 + 2048 + c];
    float v = a * sigmf(gg);
    st[c] = v; ls += v; lq += v*v;
  }
  float S = breduce_sum(ls, red);
  float Q = breduce_sum(lq, red);
  float mu = S / (float)N_;
  float var = Q / (float)N_ - mu*mu;
  float rstd = 1.f / sqrtf(var + 1e-5f);
  for (int ii = 0; ii < 8; ii++) {
    int c = ii*256 + tid;
    state[b*N_ + c] = (st[c] - mu)*rstd*g[c] + bvec[c];
  }
}

// ---- T5: NLM per neuron; performs trace shift-append in place ----
__global__ __launch_bounds__(256) void k_nlm(float* trace, const float* state,
                                             fp fc1_w, fp fc1_b, fp fc2_w, fp fc2_b,
                                             fp nlmT, float* act) {
  int n = blockIdx.x, tid = threadIdx.x;
  __shared__ float tr[B_][M_];
  __shared__ float uu[256][17];
  __shared__ float h1[128][17];
  __shared__ float vout[B_][2];
  for (int i = tid; i < B_*M_; i += 256) {
    int b = i / M_, m = i % M_;
    tr[b][m] = (m < M_-1) ? trace[((size_t)(b*N_ + n))*M_ + m + 1] : state[b*N_ + n];
  }
  __syncthreads();
  // write back shifted trace (block n exclusively owns rows (b,n))
  for (int i = tid; i < B_*M_; i += 256) {
    int b = i / M_, m = i % M_;
    trace[((size_t)(b*N_ + n))*M_ + m] = tr[b][m];
  }
  float w25[M_];
  for (int m = 0; m < M_; m++) w25[m] = fc1_w[((size_t)n*M_ + m)*256 + tid];
  float bias = fc1_b[n*256 + tid];
  for (int b = 0; b < B_; b++) {
    float u = bias;
    for (int m = 0; m < M_; m++) u += tr[b][m]*w25[m];
    uu[tid][b] = u;
  }
  __syncthreads();
  if (tid < 128) {
    for (int b = 0; b < B_; b++)
      h1[tid][b] = uu[tid][b] * sigmf(uu[tid + 128][b]);
  }
  __syncthreads();
  if (tid < 32) {
    int b = tid >> 1, o = tid & 1;
    float acc = fc2_b[n*2 + o];
    for (int hh = 0; hh < 128; hh++) acc += h1[hh][b] * fc2_w[((size_t)n*128 + hh)*2 + o];
    vout[b][o] = acc;
  }
  __syncthreads();
  if (tid < B_) {
    act[tid*N_ + n] = vout[tid][0] * sigmf(vout[tid][1]) / nlmT[0];
  }
}

// ---- T6: out sync + wave-coop pred GEMV ----
__global__ __launch_bounds__(256) void k_outsync(const float* act, float* ao, float* bo,
                                                 fp decay_o, const int* L, const int* R,
                                                 fp out_w, fp out_b, float* predsf, int t) {
  int b = blockIdx.x, tid = threadIdx.x, wave = tid >> 6, lane = tid & 63;
  __shared__ float sout[1024];
  for (int cc = 0; cc < 4; cc++) {
    int s_ = tid + cc*256;
    float r = expf(-decay_o[s_]);
    float pair = act[b*N_ + L[s_]] * act[b*N_ + R[s_]];
    float a  = r*ao[b*SO_ + s_] + pair;
    float bt = r*bo[b*SO_ + s_] + 1.f;
    ao[b*SO_ + s_] = a; bo[b*SO_ + s_] = bt;
    sout[s_] = a / sqrtf(bt);
  }
  __syncthreads();
  for (int r = wave*250; r < wave*250 + 250; r++) {
    const float* wr = out_w + (size_t)r*1024 + lane*4;
    const float* pp = sout + lane*4;
    float s = f4dot(*(const float4*)(wr),       *(const float4*)(pp))
            + f4dot(*(const float4*)(wr + 256), *(const float4*)(pp + 256))
            + f4dot(*(const float4*)(wr + 512), *(const float4*)(pp + 512))
            + f4dot(*(const float4*)(wr + 768), *(const float4*)(pp + 768));
    s = wred(s);
    if (lane == 0) predsf[((size_t)(t*B_ + b))*O_ + r] = s + out_b[r];
  }
}

// ---- T7: entropy + f32 output ----
__global__ __launch_bounds__(256) void k_final(const float* predsf, float* out) {
  int b = blockIdx.x, t = blockIdx.y, tid = threadIdx.x;
  __shared__ float red[256];
  const float* p = predsf + ((size_t)(t*B_ + b))*O_;
  float lm = -1e30f;
  for (int o = tid; o < O_; o += 256) lm = fmaxf(lm, p[o]);
  float Mx = breduce_max(lm, red);
  float le = 0.f;
  for (int o = tid; o < O_; o += 256) le += expf(p[o] - Mx);
  float S = breduce_sum(le, red);
  float lt = 0.f;
  for (int o = tid; o < O_; o += 256) {
    float pr = expf(p[o] - Mx) / S;
    lt += pr * logf(pr + 1e-10f);
  }
  float E = breduce_sum(lt, red);
  float ent = -E / logf((float)O_);
  for (int o = tid; o < O_; o += 256)
    out[(size_t)b*O_*T_ + (size_t)o*T_ + t] = p[o];
  if (tid == 0)
    out[(size_t)B_*O_*T_ + b*T_ + t] = ent;
}

extern "C" void kernel_launch(void* const* d_in, const int* in_sizes, int n_in,
                              void* d_out, int out_size, void* d_ws, size_t ws_size,
                              hipStream_t stream) {
  (void)in_sizes; (void)n_in; (void)out_size; (void)ws_size;
  fp x          = (fp)d_in[0];
  fp conv_w     = (fp)d_in[1];
  fp conv_b     = (fp)d_in[2];
  fp patch_ln_g = (fp)d_in[3];
  fp patch_ln_b = (fp)d_in[4];
  fp pos        = (fp)d_in[5];
  fp kv_w       = (fp)d_in[6];
  fp kv_b       = (fp)d_in[7];
  fp kv_ln_g    = (fp)d_in[8];
  fp kv_ln_b    = (fp)d_in[9];
  fp q_w        = (fp)d_in[10];
  fp q_b        = (fp)d_in[11];
  fp attn_in_w  = (fp)d_in[12];
  fp attn_in_b  = (fp)d_in[13];
  fp attn_out_w = (fp)d_in[14];
  fp attn_out_b = (fp)d_in[15];
  fp syn_w      = (fp)d_in[16];
  fp syn_b      = (fp)d_in[17];
  fp syn_ln_g   = (fp)d_in[18];
  fp syn_ln_b   = (fp)d_in[19];
  fp fc1_w      = (fp)d_in[20];
  fp fc1_b      = (fp)d_in[21];
  fp fc2_w      = (fp)d_in[22];
  fp fc2_b      = (fp)d_in[23];
  fp nlm_T      = (fp)d_in[24];
  fp start_state= (fp)d_in[25];
  fp start_trace= (fp)d_in[26];
  fp decay_a    = (fp)d_in[27];
  fp decay_o    = (fp)d_in[28];
  fp out_w      = (fp)d_in[29];
  fp out_b      = (fp)d_in[30];
  const int* act_left  = (const int*)d_in[31];
  const int* act_right = (const int*)d_in[32];
  const int* out_left  = (const int*)d_in[33];
  const int* out_right = (const int*)d_in[34];

  float* ws = (float*)d_ws;
  float* X   = ws;
  float* kvb = ws + (size_t)B_*P_*D_;          // 1,605,632 floats

  float* pt     = X;                           // precompute only (dead after k_kv)
  float* predsf = X;                           // 256,000
  float* act    = X + 256000;                  // 32,768
  float* trace  = X + 288768;                  // 819,200
  float* aa     = X + 1107968;                 // 8,192
  float* ba     = X + 1116160;                 // 8,192
  float* ao     = X + 1124352;                 // 16,384
  float* bo     = X + 1140736;                 // 16,384
  float* qh     = X + 1157120;                 // 8,192
  float* attn_o = X + 1165312;                 // 8,192
  float* ysyn   = X + 1173504;                 // 65,536
  float* state  = X + 1239040;                 // 32,768
  float* zz     = X + 1271808;                 // 65,536 -> ends 1,337,344 < 1,605,632

  k_patch<<<dim3(B_*P_/4), dim3(256), 0, stream>>>(x, conv_w, conv_b, patch_ln_g, patch_ln_b, pos, pt);
  k_kv<<<dim3(B_*P_/4), dim3(256), 0, stream>>>(pt, kv_w, kv_b, kv_ln_g, kv_ln_b, kvb);
  k_init<<<dim3((B_*N_*M_ + 255)/256), dim3(256), 0, stream>>>(start_state, start_trace,
        out_left, out_right, act, trace, aa, ba, ao, bo);

  for (int t = 0; t < T_; t++) {
    k_syncq<<<dim3(B_), dim3(256), 0, stream>>>(act, aa, ba, decay_a, act_left, act_right,
                                                q_w, q_b, attn_in_w, attn_in_b, qh);
    k_attn<<<dim3(B_, H_), dim3(256), 0, stream>>>(qh, kvb, attn_in_w, attn_in_b, zz);
    k_ao<<<dim3(B_), dim3(256), 0, stream>>>(zz, attn_in_w, attn_in_b,
                                             attn_out_w, attn_out_b, attn_o);
    k_syn<<<dim3(32, 2), dim3(256), 0, stream>>>(attn_o, act, syn_w, syn_b, ysyn);
    k_state<<<dim3(B_), dim3(256), 0, stream>>>(ysyn, syn_ln_g, syn_ln_b, state);
    k_nlm<<<dim3(N_), dim3(256), 0, stream>>>(trace, state, fc1_w, fc1_b, fc2_w, fc2_b,
                                              nlm_T, act);
    k_outsync<<<dim3(B_), dim3(256), 0, stream>>>(act, ao, bo, decay_o, out_left, out_right,
                                                  out_w, out_b, predsf, t);
  }
  k_final<<<dim3(B_, T_), dim3(256), 0, stream>>>(predsf, (float*)d_out);
}